// Round 1
// baseline (2127.286 us; speedup 1.0000x reference)
//
#include <hip/hip_runtime.h>
#include <hip/hip_bf16.h>
#include <math.h>

namespace {
constexpr int kB  = 2;
constexpr int kS  = 2048;
constexpr int kD  = 1024;
constexpr int kH  = 16;
constexpr int kDK = 64;
constexpr int kDV = 64;
constexpr int kDFF = 4096;
constexpr float kEps = 1e-6f;
constexpr int kM = kB * kS; // 4096 total rows
}

// ---------------------------------------------------------------------------
// LayerNorm: one block per row, 256 threads, D=1024 (4 floats/thread, float4)
// ---------------------------------------------------------------------------
__global__ __launch_bounds__(256) void ln_kernel(
    const float* __restrict__ x, const float* __restrict__ g,
    const float* __restrict__ b, float* __restrict__ out)
{
    const size_t row = blockIdx.x;
    const float4 v = ((const float4*)(x + row * kD))[threadIdx.x];
    float s = v.x + v.y + v.z + v.w;
    float q = v.x * v.x + v.y * v.y + v.z * v.z + v.w * v.w;
#pragma unroll
    for (int off = 32; off > 0; off >>= 1) {
        s += __shfl_down(s, off);
        q += __shfl_down(q, off);
    }
    __shared__ float rs[4], rq[4];
    const int wid = threadIdx.x >> 6, lane = threadIdx.x & 63;
    if (lane == 0) { rs[wid] = s; rq[wid] = q; }
    __syncthreads();
    const float ts = rs[0] + rs[1] + rs[2] + rs[3];
    const float tq = rq[0] + rq[1] + rq[2] + rq[3];
    const float mean = ts * (1.0f / kD);
    const float var  = tq * (1.0f / kD) - mean * mean;
    const float rstd = rsqrtf(var + kEps);
    const float4 gg = ((const float4*)g)[threadIdx.x];
    const float4 bb = ((const float4*)b)[threadIdx.x];
    float4 o;
    o.x = (v.x - mean) * rstd * gg.x + bb.x;
    o.y = (v.y - mean) * rstd * gg.y + bb.y;
    o.z = (v.z - mean) * rstd * gg.z + bb.z;
    o.w = (v.w - mean) * rstd * gg.w + bb.w;
    ((float4*)(out + row * kD))[threadIdx.x] = o;
}

// ---------------------------------------------------------------------------
// Row softmax over 2048 elements, in place. One block (256 thr) per row.
// ---------------------------------------------------------------------------
__global__ __launch_bounds__(256) void softmax2048(float* __restrict__ p)
{
    float* pr = p + (size_t)blockIdx.x * kS;
    float4 v0 = ((const float4*)pr)[threadIdx.x];
    float4 v1 = ((const float4*)pr)[threadIdx.x + 256];
    float m = fmaxf(fmaxf(fmaxf(v0.x, v0.y), fmaxf(v0.z, v0.w)),
                    fmaxf(fmaxf(v1.x, v1.y), fmaxf(v1.z, v1.w)));
#pragma unroll
    for (int off = 32; off > 0; off >>= 1) m = fmaxf(m, __shfl_down(m, off));
    __shared__ float red[4];
    __shared__ float red2[4];
    const int wid = threadIdx.x >> 6, lane = threadIdx.x & 63;
    if (lane == 0) red[wid] = m;
    __syncthreads();
    m = fmaxf(fmaxf(red[0], red[1]), fmaxf(red[2], red[3]));
    v0.x = __expf(v0.x - m); v0.y = __expf(v0.y - m);
    v0.z = __expf(v0.z - m); v0.w = __expf(v0.w - m);
    v1.x = __expf(v1.x - m); v1.y = __expf(v1.y - m);
    v1.z = __expf(v1.z - m); v1.w = __expf(v1.w - m);
    float s = v0.x + v0.y + v0.z + v0.w + v1.x + v1.y + v1.z + v1.w;
#pragma unroll
    for (int off = 32; off > 0; off >>= 1) s += __shfl_down(s, off);
    if (lane == 0) red2[wid] = s;
    __syncthreads();
    const float tot = red2[0] + red2[1] + red2[2] + red2[3];
    const float inv = 1.0f / tot;
    v0.x *= inv; v0.y *= inv; v0.z *= inv; v0.w *= inv;
    v1.x *= inv; v1.y *= inv; v1.z *= inv; v1.w *= inv;
    ((float4*)pr)[threadIdx.x]       = v0;
    ((float4*)pr)[threadIdx.x + 256] = v1;
}

// ---------------------------------------------------------------------------
// Tiled f32 GEMM. C[M,N] = A[M,K] @ op(B) (+bias)(+gelu)(+res), 64x64x16 tile,
// 256 threads, 4x4 micro-tile. BT=true: B is W[N,K] (torch Linear, NT GEMM).
// BT=false: B is [K,N] (NN GEMM).
// MODE 0: plain. MODE 1: scores batched per (b,h). MODE 2: ctx batched (b,h).
// ---------------------------------------------------------------------------
template<int MODE, bool BT, bool BIAS, bool RES, bool GELU_ACT, bool SCALED>
__global__ __launch_bounds__(256) void gemm64(
    const float* __restrict__ Abase, int lda,
    const float* __restrict__ Bbase, int ldb,
    float* __restrict__ Cbase, int ldc,
    const float* __restrict__ bias,
    const float* __restrict__ resbase, int ldres,
    int M, int N, int K, float scale)
{
    __shared__ __align__(16) float As[16][68];
    __shared__ __align__(16) float Bs[16][68];

    const float* A = Abase;
    const float* Bm = Bbase;
    float* C = Cbase;
    const float* R = resbase;

    if (MODE == 1) {
        const int z = blockIdx.z; const int b = z >> 4; const int h = z & 15;
        const size_t qoff = (size_t)b * kS * (kH * kDK) + (size_t)h * kDK;
        A += qoff; Bm += qoff;
        C += (size_t)z * kS * kS;
    } else if (MODE == 2) {
        const int z = blockIdx.z; const int b = z >> 4; const int h = z & 15;
        A += (size_t)z * kS * kS;
        const size_t voff = (size_t)b * kS * (kH * kDV) + (size_t)h * kDV;
        Bm += voff; C += voff;
    }

    const int m0 = blockIdx.y * 64;
    const int n0 = blockIdx.x * 64;
    const int t  = threadIdx.x;
    const int ty = t >> 4;   // 0..15 (m micro-row)
    const int tx = t & 15;   // 0..15 (n micro-col)
    const int ar = t >> 2;   // 0..63 (row for tile loads)
    const int aq = t & 3;    // 0..3  (k quad)

    float acc[4][4] = {};

    for (int k0 = 0; k0 < K; k0 += 16) {
        const float4 av = *(const float4*)(A + (size_t)(m0 + ar) * lda + k0 + aq * 4);
        As[aq * 4 + 0][ar] = av.x;
        As[aq * 4 + 1][ar] = av.y;
        As[aq * 4 + 2][ar] = av.z;
        As[aq * 4 + 3][ar] = av.w;
        if (BT) {
            const float4 bv = *(const float4*)(Bm + (size_t)(n0 + ar) * ldb + k0 + aq * 4);
            Bs[aq * 4 + 0][ar] = bv.x;
            Bs[aq * 4 + 1][ar] = bv.y;
            Bs[aq * 4 + 2][ar] = bv.z;
            Bs[aq * 4 + 3][ar] = bv.w;
        } else {
            const int kr = t >> 4;  // 0..15
            const int c  = t & 15;  // 0..15
            const float4 bv = *(const float4*)(Bm + (size_t)(k0 + kr) * ldb + n0 + c * 4);
            *(float4*)&Bs[kr][c * 4] = bv;
        }
        __syncthreads();
#pragma unroll
        for (int kk = 0; kk < 16; ++kk) {
            const float4 a = *(const float4*)&As[kk][ty * 4];
            const float4 w = *(const float4*)&Bs[kk][tx * 4];
            acc[0][0] += a.x * w.x; acc[0][1] += a.x * w.y; acc[0][2] += a.x * w.z; acc[0][3] += a.x * w.w;
            acc[1][0] += a.y * w.x; acc[1][1] += a.y * w.y; acc[1][2] += a.y * w.z; acc[1][3] += a.y * w.w;
            acc[2][0] += a.z * w.x; acc[2][1] += a.z * w.y; acc[2][2] += a.z * w.z; acc[2][3] += a.z * w.w;
            acc[3][0] += a.w * w.x; acc[3][1] += a.w * w.y; acc[3][2] += a.w * w.z; acc[3][3] += a.w * w.w;
        }
        __syncthreads();
    }

#pragma unroll
    for (int i = 0; i < 4; ++i) {
        const int gm = m0 + ty * 4 + i;
#pragma unroll
        for (int j = 0; j < 4; ++j) {
            const int gn = n0 + tx * 4 + j;
            float v = acc[i][j];
            if (SCALED)   v *= scale;
            if (BIAS)     v += bias[gn];
            if (GELU_ACT) v = 0.5f * v * (1.0f + erff(v * 0.7071067811865476f));
            if (RES)      v += R[(size_t)gm * ldres + gn];
            C[(size_t)gm * ldc + gn] = v;
        }
    }
}

// ---------------------------------------------------------------------------
extern "C" void kernel_launch(void* const* d_in, const int* in_sizes, int n_in,
                              void* d_out, int out_size, void* d_ws, size_t ws_size,
                              hipStream_t stream) {
    (void)in_sizes; (void)n_in; (void)out_size; (void)ws_size;

    const float* x      = (const float*)d_in[0];
    const float* w_qs   = (const float*)d_in[1];
    const float* w_ks   = (const float*)d_in[2];
    const float* w_vs   = (const float*)d_in[3];
    const float* fc_w   = (const float*)d_in[4];
    const float* fc_b   = (const float*)d_in[5];
    const float* ln1_g  = (const float*)d_in[6];
    const float* ln1_b  = (const float*)d_in[7];
    const float* ffn_w1 = (const float*)d_in[8];
    const float* ffn_b1 = (const float*)d_in[9];
    const float* ffn_w2 = (const float*)d_in[10];
    const float* ffn_b2 = (const float*)d_in[11];
    const float* ln2_g  = (const float*)d_in[12];
    const float* ln2_b  = (const float*)d_in[13];

    float* out_enc  = (float*)d_out;                       // [B,S,D]
    float* out_attn = out_enc + (size_t)kB * kS * kD;      // [B,H,S,S]

    // Workspace layout (f32): 4 x 16MB slabs + 1 x 64MB slab = 128MB total.
    float* ws  = (float*)d_ws;
    float* S0 = ws;                           // q_in (LN1 out), later h (LN2 out)
    float* S1 = S0 + (size_t)kM * kD;         // Q, later ctx
    float* S2 = S1 + (size_t)kM * kD;         // K, later attn_out (FFN residual)
    float* S3 = S2 + (size_t)kM * kD;         // V
    float* S4 = S3 + (size_t)kM * kD;         // gelu(ffn1) out [4096,4096]

    const dim3 blk(256);

    // 1. q_in = LN1(x)
    ln_kernel<<<kM, blk, 0, stream>>>(x, ln1_g, ln1_b, S0);

    // 2. Q = q_in @ w_qs^T ; K = x @ w_ks^T ; V = x @ w_vs^T   [4096,1024]
    gemm64<0, true, false, false, false, false><<<dim3(16, 64, 1), blk, 0, stream>>>(
        S0, kD, w_qs, kD, S1, kD, nullptr, nullptr, 0, kM, kD, kD, 1.0f);
    gemm64<0, true, false, false, false, false><<<dim3(16, 64, 1), blk, 0, stream>>>(
        x, kD, w_ks, kD, S2, kD, nullptr, nullptr, 0, kM, kD, kD, 1.0f);
    gemm64<0, true, false, false, false, false><<<dim3(16, 64, 1), blk, 0, stream>>>(
        x, kD, w_vs, kD, S3, kD, nullptr, nullptr, 0, kM, kD, kD, 1.0f);

    // 3. scores = scale * Q K^T per (b,h) -> out_attn  [32 x 2048 x 2048]
    gemm64<1, true, false, false, false, true><<<dim3(32, 32, kB * kH), blk, 0, stream>>>(
        S1, kH * kDK, S2, kH * kDK, out_attn, kS, nullptr, nullptr, 0,
        kS, kS, kDK, 0.125f);

    // 4. softmax rows, in place
    softmax2048<<<kB * kH * kS, blk, 0, stream>>>(out_attn);

    // 5. ctx = attn @ V per (b,h) -> S1 (overwrites Q), layout [B,S,H*DV]
    gemm64<2, false, false, false, false, false><<<dim3(1, 32, kB * kH), blk, 0, stream>>>(
        out_attn, kS, S3, kH * kDV, S1, kH * kDV, nullptr, nullptr, 0,
        kS, kDV, kS, 1.0f);

    // 6. attn_out = ctx @ fc_w^T + fc_b + x -> S2 (overwrites K)
    gemm64<0, true, true, true, false, false><<<dim3(16, 64, 1), blk, 0, stream>>>(
        S1, kD, fc_w, kD, S2, kD, fc_b, x, kD, kM, kD, kD, 1.0f);

    // 7. h = LN2(attn_out) -> S0
    ln_kernel<<<kM, blk, 0, stream>>>(S2, ln2_g, ln2_b, S0);

    // 8. g = gelu(h @ ffn_w1^T + b1) -> S4  [4096,4096]
    gemm64<0, true, true, false, true, false><<<dim3(64, 64, 1), blk, 0, stream>>>(
        S0, kD, ffn_w1, kD, S4, kDFF, ffn_b1, nullptr, 0, kM, kDFF, kD, 1.0f);

    // 9. enc_out = g @ ffn_w2^T + b2 + attn_out -> out_enc
    gemm64<0, true, true, true, false, false><<<dim3(16, 64, 1), blk, 0, stream>>>(
        S4, kDFF, ffn_w2, kDFF, out_enc, kD, ffn_b2, S2, kD, kM, kD, kDFF, 1.0f);
}

// Round 2
// 849.054 us; speedup vs baseline: 2.5055x; 2.5055x over previous
//
#include <hip/hip_runtime.h>
#include <hip/hip_bf16.h>
#include <math.h>

typedef __attribute__((ext_vector_type(8))) short bf16x8;   // 8 bf16 in 4 VGPRs (guide §3)
typedef __attribute__((ext_vector_type(4))) float f32x4;
typedef __attribute__((ext_vector_type(4))) unsigned short u16x4;

namespace {
constexpr int kB = 2, kS = 2048, kD = 1024, kH = 16, kDK = 64, kDV = 64, kDFF = 4096;
constexpr float kEps = 1e-6f;
constexpr int kM = kB * kS;  // 4096
}

__device__ inline unsigned short f2bf(float f) {
    unsigned int u = __builtin_bit_cast(unsigned int, f);
    u += 0x7fffu + ((u >> 16) & 1u);   // round-nearest-even
    return (unsigned short)(u >> 16);
}

__device__ inline void gload_lds16(const void* g, void* l) {
    __builtin_amdgcn_global_load_lds(
        (const __attribute__((address_space(1))) unsigned int*)g,
        (__attribute__((address_space(3))) unsigned int*)l, 16, 0, 0);
}

// ---------------------------------------------------------------------------
// f32 -> bf16 convert, vectorized (float4 in, 4x bf16 out)
// ---------------------------------------------------------------------------
__global__ __launch_bounds__(256) void cvt_bf16_kernel(
    const float* __restrict__ in, unsigned short* __restrict__ out, int n4)
{
    int i = blockIdx.x * 256 + threadIdx.x;
    const int stride = gridDim.x * 256;
    for (; i < n4; i += stride) {
        const float4 v = ((const float4*)in)[i];
        u16x4 o;
        o.x = f2bf(v.x); o.y = f2bf(v.y); o.z = f2bf(v.z); o.w = f2bf(v.w);
        ((u16x4*)out)[i] = o;
    }
}

// ---------------------------------------------------------------------------
// LayerNorm (f32 in, bf16 out): one block per row, 256 threads, D=1024
// ---------------------------------------------------------------------------
__global__ __launch_bounds__(256) void ln_bf16_kernel(
    const float* __restrict__ x, const float* __restrict__ g,
    const float* __restrict__ b, unsigned short* __restrict__ out)
{
    const size_t row = blockIdx.x;
    const float4 v = ((const float4*)(x + row * kD))[threadIdx.x];
    float s = v.x + v.y + v.z + v.w;
    float q = v.x * v.x + v.y * v.y + v.z * v.z + v.w * v.w;
#pragma unroll
    for (int off = 32; off > 0; off >>= 1) {
        s += __shfl_down(s, off);
        q += __shfl_down(q, off);
    }
    __shared__ float rs[4], rq[4];
    const int wid = threadIdx.x >> 6, lane = threadIdx.x & 63;
    if (lane == 0) { rs[wid] = s; rq[wid] = q; }
    __syncthreads();
    const float ts = rs[0] + rs[1] + rs[2] + rs[3];
    const float tq = rq[0] + rq[1] + rq[2] + rq[3];
    const float mean = ts * (1.0f / kD);
    const float var  = tq * (1.0f / kD) - mean * mean;
    const float rstd = rsqrtf(var + kEps);
    const float4 gg = ((const float4*)g)[threadIdx.x];
    const float4 bb = ((const float4*)b)[threadIdx.x];
    u16x4 o;
    o.x = f2bf((v.x - mean) * rstd * gg.x + bb.x);
    o.y = f2bf((v.y - mean) * rstd * gg.y + bb.y);
    o.z = f2bf((v.z - mean) * rstd * gg.z + bb.z);
    o.w = f2bf((v.w - mean) * rstd * gg.w + bb.w);
    ((u16x4*)(out + row * kD))[threadIdx.x] = o;
}

// ---------------------------------------------------------------------------
// Row softmax over 2048 f32, in place (d_out attn region)
// ---------------------------------------------------------------------------
__global__ __launch_bounds__(256) void softmax2048(float* __restrict__ p)
{
    float* pr = p + (size_t)blockIdx.x * kS;
    float4 v0 = ((const float4*)pr)[threadIdx.x];
    float4 v1 = ((const float4*)pr)[threadIdx.x + 256];
    float m = fmaxf(fmaxf(fmaxf(v0.x, v0.y), fmaxf(v0.z, v0.w)),
                    fmaxf(fmaxf(v1.x, v1.y), fmaxf(v1.z, v1.w)));
#pragma unroll
    for (int off = 32; off > 0; off >>= 1) m = fmaxf(m, __shfl_down(m, off));
    __shared__ float red[4], red2[4];
    const int wid = threadIdx.x >> 6, lane = threadIdx.x & 63;
    if (lane == 0) red[wid] = m;
    __syncthreads();
    m = fmaxf(fmaxf(red[0], red[1]), fmaxf(red[2], red[3]));
    v0.x = __expf(v0.x - m); v0.y = __expf(v0.y - m);
    v0.z = __expf(v0.z - m); v0.w = __expf(v0.w - m);
    v1.x = __expf(v1.x - m); v1.y = __expf(v1.y - m);
    v1.z = __expf(v1.z - m); v1.w = __expf(v1.w - m);
    float s = v0.x + v0.y + v0.z + v0.w + v1.x + v1.y + v1.z + v1.w;
#pragma unroll
    for (int off = 32; off > 0; off >>= 1) s += __shfl_down(s, off);
    if (lane == 0) red2[wid] = s;
    __syncthreads();
    const float inv = 1.0f / (red2[0] + red2[1] + red2[2] + red2[3]);
    v0.x *= inv; v0.y *= inv; v0.z *= inv; v0.w *= inv;
    v1.x *= inv; v1.y *= inv; v1.z *= inv; v1.w *= inv;
    ((float4*)pr)[threadIdx.x]       = v0;
    ((float4*)pr)[threadIdx.x + 256] = v1;
}

// ---------------------------------------------------------------------------
// bf16 MFMA GEMM (m97 structure): C[M,N] = A[M,K] @ B[N,K]^T (NT).
// 128 x BN tile, BK=32, 4 waves (2x2), 16x16x32 MFMA, global_load_lds(16B).
// MODE 0: plain. MODE 1: scores per (b,h). MODE 2: PV per (b,h), A is f32
// (reg-staged with on-the-fly bf16 convert).
// Epilogue: SCALED -> BIAS -> GELU -> RES; OUTB stores bf16 (TRANS: to Vt).
// ---------------------------------------------------------------------------
template<int MODE, int BN, bool AF32, bool OUTB, bool TRANS, bool BIAS,
         bool RES, bool GELU, bool SCALED>
__global__ __launch_bounds__(256) void gemm_mfma(
    const void* __restrict__ Abase, int lda,
    const unsigned short* __restrict__ Bbase, int ldb,
    void* __restrict__ Cbase, int ldc,
    const float* __restrict__ bias,
    const float* __restrict__ resbase, int ldres,
    int K, float scale)
{
    __shared__ __align__(16) unsigned short As[128 * 32];
    __shared__ __align__(16) unsigned short Bs[BN * 32];

    const unsigned short* A = (const unsigned short*)Abase;
    const float* Af = (const float*)Abase;
    const unsigned short* B = Bbase;
    float* Cf = (float*)Cbase;
    unsigned short* Cu = (unsigned short*)Cbase;

    if (MODE == 1) {
        const int z = blockIdx.z, b = z >> 4, h = z & 15;
        const size_t off = (size_t)b * kS * kD + (size_t)h * kDK;
        A += off; B += off;
        Cf += (size_t)z * kS * kS;
    } else if (MODE == 2) {
        const int z = blockIdx.z, b = z >> 4, h = z & 15;
        Af += (size_t)z * kS * kS;
        B  += ((size_t)b * kD + (size_t)h * kDV) * kS;   // Vt rows for this (b,h)
        Cu += (size_t)b * kS * kD + (size_t)h * kDV;
    }

    const int m0 = blockIdx.y * 128;
    const int n0 = blockIdx.x * BN;
    const int t = threadIdx.x;
    const int w = t >> 6, lane = t & 63;
    const int wm = (w >> 1) * 64;
    const int wn = (w & 1) * (BN / 2);
    constexpr int AN = (BN / 2) / 16;     // 4 for BN=128, 2 for BN=64

    f32x4 acc[4][AN];
#pragma unroll
    for (int m = 0; m < 4; ++m)
#pragma unroll
        for (int n = 0; n < AN; ++n) acc[m][n] = (f32x4){0.f, 0.f, 0.f, 0.f};

    for (int k0 = 0; k0 < K; k0 += 32) {
        // ---- stage A tile [128][32] ----
        if constexpr (!AF32) {
#pragma unroll
            for (int i = 0; i < 2; ++i) {
                const int r = i * 64 + (t >> 2);
                gload_lds16(A + (size_t)(m0 + r) * lda + k0 + (t & 3) * 8,
                            As + r * 32 + (t & 3) * 8);
            }
        } else {
#pragma unroll
            for (int i = 0; i < 4; ++i) {
                const int r = i * 32 + (t >> 3);
                const int c = (t & 7) * 4;
                const float4 v = *(const float4*)(Af + (size_t)(m0 + r) * lda + k0 + c);
                u16x4 o;
                o.x = f2bf(v.x); o.y = f2bf(v.y); o.z = f2bf(v.z); o.w = f2bf(v.w);
                *(u16x4*)(As + r * 32 + c) = o;
            }
        }
        // ---- stage B tile [BN][32] ----
#pragma unroll
        for (int i = 0; i < BN / 64; ++i) {
            const int r = i * 64 + (t >> 2);
            gload_lds16(B + (size_t)(n0 + r) * ldb + k0 + (t & 3) * 8,
                        Bs + r * 32 + (t & 3) * 8);
        }
        __syncthreads();

        bf16x8 a[4], bb[AN];
#pragma unroll
        for (int m = 0; m < 4; ++m)
            a[m] = *(const bf16x8*)(As + (wm + m * 16 + (lane & 15)) * 32 + (lane >> 4) * 8);
#pragma unroll
        for (int n = 0; n < AN; ++n)
            bb[n] = *(const bf16x8*)(Bs + (wn + n * 16 + (lane & 15)) * 32 + (lane >> 4) * 8);
#pragma unroll
        for (int m = 0; m < 4; ++m)
#pragma unroll
            for (int n = 0; n < AN; ++n)
                acc[m][n] = __builtin_amdgcn_mfma_f32_16x16x32_bf16(a[m], bb[n], acc[m][n], 0, 0, 0);
        __syncthreads();
    }

    // ---- epilogue: C/D layout col=lane&15, row=(lane>>4)*4+j (m89-verified) ----
    const int col = lane & 15, rb = (lane >> 4) * 4;
#pragma unroll
    for (int m = 0; m < 4; ++m)
#pragma unroll
        for (int n = 0; n < AN; ++n)
#pragma unroll
            for (int j = 0; j < 4; ++j) {
                const int gm = m0 + wm + m * 16 + rb + j;
                const int gn = n0 + wn + n * 16 + col;
                float v = acc[m][n][j];
                if (SCALED) v *= scale;
                if (BIAS)   v += bias[gn];
                if (GELU)   v = 0.5f * v * (1.0f + erff(v * 0.7071067811865476f));
                if (RES)    v += resbase[(size_t)gm * ldres + gn];
                if (OUTB) {
                    if (TRANS)  // V^T: [B][H*DV][S]
                        Cu[((size_t)(gm >> 11) * kD + gn) * kS + (gm & 2047)] = f2bf(v);
                    else
                        Cu[(size_t)gm * ldc + gn] = f2bf(v);
                } else {
                    Cf[(size_t)gm * ldc + gn] = v;
                }
            }
}

// ---------------------------------------------------------------------------
extern "C" void kernel_launch(void* const* d_in, const int* in_sizes, int n_in,
                              void* d_out, int out_size, void* d_ws, size_t ws_size,
                              hipStream_t stream) {
    (void)in_sizes; (void)n_in; (void)out_size; (void)ws_size;

    const float* x      = (const float*)d_in[0];
    const float* w_qs   = (const float*)d_in[1];
    const float* w_ks   = (const float*)d_in[2];
    const float* w_vs   = (const float*)d_in[3];
    const float* fc_w   = (const float*)d_in[4];
    const float* fc_b   = (const float*)d_in[5];
    const float* ln1_g  = (const float*)d_in[6];
    const float* ln1_b  = (const float*)d_in[7];
    const float* ffn_w1 = (const float*)d_in[8];
    const float* ffn_b1 = (const float*)d_in[9];
    const float* ffn_w2 = (const float*)d_in[10];
    const float* ffn_b2 = (const float*)d_in[11];
    const float* ln2_g  = (const float*)d_in[12];
    const float* ln2_b  = (const float*)d_in[13];

    float* out_enc  = (float*)d_out;                   // [B,S,D] f32
    float* out_attn = out_enc + (size_t)kM * kD;       // [B,H,S,S] f32

    // Workspace (exactly 128 MB, same footprint as round 1)
    unsigned short* xb   = (unsigned short*)d_ws;      // x bf16        4M
    unsigned short* qinb = xb   + (size_t)4194304;     // LN1(x)        4M
    unsigned short* Qb   = qinb + (size_t)4194304;     // Q             4M
    unsigned short* Kb   = Qb   + (size_t)4194304;     // K             4M
    unsigned short* Vt   = Kb   + (size_t)4194304;     // V^T           4M
    unsigned short* ctxb = Vt   + (size_t)4194304;     // ctx           4M
    unsigned short* hb   = ctxb + (size_t)4194304;     // LN2(attn_out) 4M
    unsigned short* gb   = hb   + (size_t)4194304;     // gelu out      16M
    unsigned short* wqsb = gb   + (size_t)16777216;    // weights bf16
    unsigned short* wksb = wqsb + (size_t)1048576;
    unsigned short* wvsb = wksb + (size_t)1048576;
    unsigned short* fcwb = wvsb + (size_t)1048576;
    unsigned short* w1b  = fcwb + (size_t)1048576;     // 4M
    unsigned short* w2b  = w1b  + (size_t)4194304;     // 4M
    float* attn_out      = (float*)(w2b + (size_t)4194304);  // f32 16MB

    const dim3 blk(256);

    // ---- converts ----
    cvt_bf16_kernel<<<2048, blk, 0, stream>>>(x, xb, kM * kD / 4);
    cvt_bf16_kernel<<<512, blk, 0, stream>>>(w_qs, wqsb, kD * kD / 4);
    cvt_bf16_kernel<<<512, blk, 0, stream>>>(w_ks, wksb, kD * kD / 4);
    cvt_bf16_kernel<<<512, blk, 0, stream>>>(w_vs, wvsb, kD * kD / 4);
    cvt_bf16_kernel<<<512, blk, 0, stream>>>(fc_w, fcwb, kD * kD / 4);
    cvt_bf16_kernel<<<2048, blk, 0, stream>>>(ffn_w1, w1b, kDFF * kD / 4);
    cvt_bf16_kernel<<<2048, blk, 0, stream>>>(ffn_w2, w2b, kDFF * kD / 4);

    // ---- LN1 ----
    ln_bf16_kernel<<<kM, blk, 0, stream>>>(x, ln1_g, ln1_b, qinb);

    // ---- Q/K/V projections (NT, bf16 out; V transposed) ----
    gemm_mfma<0, 128, false, true, false, false, false, false, false>
        <<<dim3(8, 32), blk, 0, stream>>>(qinb, kD, wqsb, kD, Qb, kD,
                                          nullptr, nullptr, 0, kD, 1.0f);
    gemm_mfma<0, 128, false, true, false, false, false, false, false>
        <<<dim3(8, 32), blk, 0, stream>>>(xb, kD, wksb, kD, Kb, kD,
                                          nullptr, nullptr, 0, kD, 1.0f);
    gemm_mfma<0, 128, false, true, true, false, false, false, false>
        <<<dim3(8, 32), blk, 0, stream>>>(xb, kD, wvsb, kD, Vt, 0,
                                          nullptr, nullptr, 0, kD, 1.0f);

    // ---- scores = scale * Q K^T -> out_attn (f32) ----
    gemm_mfma<1, 128, false, false, false, false, false, false, true>
        <<<dim3(16, 16, kB * kH), blk, 0, stream>>>(Qb, kD, Kb, kD, out_attn, kS,
                                                    nullptr, nullptr, 0, kDK, 0.125f);

    // ---- softmax in place ----
    softmax2048<<<kB * kH * kS, blk, 0, stream>>>(out_attn);

    // ---- ctx = attn @ V (A f32 reg-staged, B = Vt) -> ctx bf16 [B,S,H*DV] ----
    gemm_mfma<2, 64, true, true, false, false, false, false, false>
        <<<dim3(1, 16, kB * kH), blk, 0, stream>>>(out_attn, kS, Vt, kS, ctxb, kD,
                                                   nullptr, nullptr, 0, kS, 1.0f);

    // ---- attn_out = ctx @ fc_w^T + fc_b + x (f32) ----
    gemm_mfma<0, 128, false, false, false, true, true, false, false>
        <<<dim3(8, 32), blk, 0, stream>>>(ctxb, kD, fcwb, kD, attn_out, kD,
                                          fc_b, x, kD, kD, 1.0f);

    // ---- LN2 ----
    ln_bf16_kernel<<<kM, blk, 0, stream>>>(attn_out, ln2_g, ln2_b, hb);

    // ---- g = gelu(h @ ffn_w1^T + b1) -> bf16 ----
    gemm_mfma<0, 128, false, true, false, true, false, true, false>
        <<<dim3(32, 32), blk, 0, stream>>>(hb, kD, w1b, kD, gb, kDFF,
                                           ffn_b1, nullptr, 0, kD, 1.0f);

    // ---- enc_out = g @ ffn_w2^T + b2 + attn_out (f32) ----
    gemm_mfma<0, 128, false, false, false, true, true, false, false>
        <<<dim3(8, 32), blk, 0, stream>>>(gb, kDFF, w2b, kDFF, out_enc, kD,
                                          ffn_b2, attn_out, kD, kDFF, 1.0f);
}

// Round 3
// 664.318 us; speedup vs baseline: 3.2022x; 1.2781x over previous
//
#include <hip/hip_runtime.h>
#include <hip/hip_bf16.h>
#include <math.h>

typedef __attribute__((ext_vector_type(8))) short bf16x8;   // 8 bf16 in 4 VGPRs
typedef __attribute__((ext_vector_type(4))) float f32x4;
typedef __attribute__((ext_vector_type(4))) unsigned short u16x4;

namespace {
constexpr int kB = 2, kS = 2048, kD = 1024, kH = 16, kDK = 64, kDV = 64, kDFF = 4096;
constexpr float kEps = 1e-6f;
constexpr int kM = kB * kS;  // 4096
}

__device__ inline unsigned short f2bf(float f) {
    unsigned int u = __builtin_bit_cast(unsigned int, f);
    u += 0x7fffu + ((u >> 16) & 1u);   // round-nearest-even
    return (unsigned short)(u >> 16);
}
__device__ inline float bf2f(unsigned short u) {
    unsigned int x = ((unsigned int)u) << 16;
    return __builtin_bit_cast(float, x);
}

__device__ inline void gload_lds16(const void* g, void* l) {
    __builtin_amdgcn_global_load_lds(
        (const __attribute__((address_space(1))) unsigned int*)g,
        (__attribute__((address_space(3))) unsigned int*)l, 16, 0, 0);
}

// ---------------------------------------------------------------------------
// f32 -> bf16 convert
// ---------------------------------------------------------------------------
__global__ __launch_bounds__(256) void cvt_bf16_kernel(
    const float* __restrict__ in, unsigned short* __restrict__ out, int n4)
{
    int i = blockIdx.x * 256 + threadIdx.x;
    const int stride = gridDim.x * 256;
    for (; i < n4; i += stride) {
        const float4 v = ((const float4*)in)[i];
        u16x4 o;
        o.x = f2bf(v.x); o.y = f2bf(v.y); o.z = f2bf(v.z); o.w = f2bf(v.w);
        ((u16x4*)out)[i] = o;
    }
}

// ---------------------------------------------------------------------------
// LayerNorm (f32 in, bf16 out): one block per row, 256 threads, D=1024
// ---------------------------------------------------------------------------
__global__ __launch_bounds__(256) void ln_bf16_kernel(
    const float* __restrict__ x, const float* __restrict__ g,
    const float* __restrict__ b, unsigned short* __restrict__ out)
{
    const size_t row = blockIdx.x;
    const float4 v = ((const float4*)(x + row * kD))[threadIdx.x];
    float s = v.x + v.y + v.z + v.w;
    float q = v.x * v.x + v.y * v.y + v.z * v.z + v.w * v.w;
#pragma unroll
    for (int off = 32; off > 0; off >>= 1) {
        s += __shfl_down(s, off);
        q += __shfl_down(q, off);
    }
    __shared__ float rs[4], rq[4];
    const int wid = threadIdx.x >> 6, lane = threadIdx.x & 63;
    if (lane == 0) { rs[wid] = s; rq[wid] = q; }
    __syncthreads();
    const float ts = rs[0] + rs[1] + rs[2] + rs[3];
    const float tq = rq[0] + rq[1] + rq[2] + rq[3];
    const float mean = ts * (1.0f / kD);
    const float var  = tq * (1.0f / kD) - mean * mean;
    const float rstd = rsqrtf(var + kEps);
    const float4 gg = ((const float4*)g)[threadIdx.x];
    const float4 bb = ((const float4*)b)[threadIdx.x];
    u16x4 o;
    o.x = f2bf((v.x - mean) * rstd * gg.x + bb.x);
    o.y = f2bf((v.y - mean) * rstd * gg.y + bb.y);
    o.z = f2bf((v.z - mean) * rstd * gg.z + bb.z);
    o.w = f2bf((v.w - mean) * rstd * gg.w + bb.w);
    ((u16x4*)(out + row * kD))[threadIdx.x] = o;
}

// ---------------------------------------------------------------------------
// bf16 MFMA GEMM (m97 structure): C[M,N] = A[M,K] @ B[N,K]^T (NT).
// 128x128 tile, BK=32, 4 waves (2x2), 16x16x32 MFMA, global_load_lds(16B).
// ---------------------------------------------------------------------------
template<bool OUTB, bool TRANS, bool BIAS, bool RES, bool GELU>
__global__ __launch_bounds__(256) void gemm_mfma(
    const unsigned short* __restrict__ A, int lda,
    const unsigned short* __restrict__ B, int ldb,
    void* __restrict__ Cbase, int ldc,
    const float* __restrict__ bias,
    const float* __restrict__ resbase, int ldres,
    int K)
{
    __shared__ __align__(16) unsigned short As[128 * 32];
    __shared__ __align__(16) unsigned short Bs[128 * 32];

    float* Cf = (float*)Cbase;
    unsigned short* Cu = (unsigned short*)Cbase;

    const int m0 = blockIdx.y * 128;
    const int n0 = blockIdx.x * 128;
    const int t = threadIdx.x;
    const int w = t >> 6, lane = t & 63;
    const int wm = (w >> 1) * 64;
    const int wn = (w & 1) * 64;

    f32x4 acc[4][4];
#pragma unroll
    for (int m = 0; m < 4; ++m)
#pragma unroll
        for (int n = 0; n < 4; ++n) acc[m][n] = (f32x4){0.f, 0.f, 0.f, 0.f};

    for (int k0 = 0; k0 < K; k0 += 32) {
#pragma unroll
        for (int i = 0; i < 2; ++i) {
            const int r = i * 64 + (t >> 2);
            gload_lds16(A + (size_t)(m0 + r) * lda + k0 + (t & 3) * 8,
                        As + r * 32 + (t & 3) * 8);
            gload_lds16(B + (size_t)(n0 + r) * ldb + k0 + (t & 3) * 8,
                        Bs + r * 32 + (t & 3) * 8);
        }
        __syncthreads();

        bf16x8 a[4], bb[4];
#pragma unroll
        for (int m = 0; m < 4; ++m)
            a[m] = *(const bf16x8*)(As + (wm + m * 16 + (lane & 15)) * 32 + (lane >> 4) * 8);
#pragma unroll
        for (int n = 0; n < 4; ++n)
            bb[n] = *(const bf16x8*)(Bs + (wn + n * 16 + (lane & 15)) * 32 + (lane >> 4) * 8);
#pragma unroll
        for (int m = 0; m < 4; ++m)
#pragma unroll
            for (int n = 0; n < 4; ++n)
                acc[m][n] = __builtin_amdgcn_mfma_f32_16x16x32_bf16(a[m], bb[n], acc[m][n], 0, 0, 0);
        __syncthreads();
    }

    const int col = lane & 15, rb = (lane >> 4) * 4;
#pragma unroll
    for (int m = 0; m < 4; ++m)
#pragma unroll
        for (int n = 0; n < 4; ++n)
#pragma unroll
            for (int j = 0; j < 4; ++j) {
                const int gm = m0 + wm + m * 16 + rb + j;
                const int gn = n0 + wn + n * 16 + col;
                float v = acc[m][n][j];
                if (BIAS) v += bias[gn];
                if (GELU) v = 0.5f * v * (1.0f + erff(v * 0.7071067811865476f));
                if (RES)  v += resbase[(size_t)gm * ldres + gn];
                if (OUTB) {
                    if (TRANS)  // V^T: [B][H*DV][S]
                        Cu[((size_t)(gm >> 11) * kD + gn) * kS + (gm & 2047)] = f2bf(v);
                    else
                        Cu[(size_t)gm * ldc + gn] = f2bf(v);
                } else {
                    Cf[(size_t)gm * ldc + gn] = v;
                }
            }
}

// ---------------------------------------------------------------------------
// Fused attention: per block = one (b,h) x one 128-row Q tile.
// Two passes over 32 K/V tiles of 64 keys. 4 waves x 32 q-rows each (wave-
// local softmax stats, no cross-wave reduce). Q pre-scaled by 1/8 (exact).
// Pass 1: online row max/sum. Pass 2: recompute S, write attn f32 (the only
// big HBM write), P->LDS bf16 (stride 72: 2-way conflicts = free), O += P*V.
// ---------------------------------------------------------------------------
__global__ __launch_bounds__(256) void fused_attn(
    const unsigned short* __restrict__ Qb,   // [B,S,H*DK] bf16
    const unsigned short* __restrict__ Kb,   // [B,S,H*DK] bf16
    const unsigned short* __restrict__ Vt,   // [B,H*DV,S] bf16
    float* __restrict__ attn,                // [B,H,S,S] f32
    unsigned short* __restrict__ ctx)        // [B,S,H*DV] bf16
{
    __shared__ __align__(16) unsigned short Ks[64][72];
    __shared__ __align__(16) unsigned short Vs[64][72];
    __shared__ __align__(16) unsigned short Ps[128][72];

    const int z = blockIdx.y, b = z >> 4, h = z & 15;
    const int qt = blockIdx.x;
    const int t = threadIdx.x, w = t >> 6, lane = t & 63;
    const int l16 = lane & 15, lhi = lane >> 4;

    const unsigned short* Qp = Qb + (size_t)b * kS * kD + (size_t)h * kDK;
    const unsigned short* Kp = Kb + (size_t)b * kS * kD + (size_t)h * kDK;
    const unsigned short* Vp = Vt + (size_t)(b * kD + h * kDV) * kS;
    float* Ap = attn + (size_t)z * kS * kS;

    // ---- Q fragments in registers, pre-scaled by 1/8 (exact in bf16) ----
    bf16x8 q[2][2];
    const int qrow0 = qt * 128 + w * 32;
#pragma unroll
    for (int mf = 0; mf < 2; ++mf)
#pragma unroll
        for (int kq = 0; kq < 2; ++kq) {
            bf16x8 v = *(const bf16x8*)(Qp + (size_t)(qrow0 + mf * 16 + l16) * kD + kq * 32 + lhi * 8);
#pragma unroll
            for (int e = 0; e < 8; ++e)
                v[e] = (short)f2bf(bf2f((unsigned short)v[e]) * 0.125f);
            q[mf][kq] = v;
        }

    float mrow[2][4], lrow[2][4];
#pragma unroll
    for (int mf = 0; mf < 2; ++mf)
#pragma unroll
        for (int j = 0; j < 4; ++j) { mrow[mf][j] = -1e30f; lrow[mf][j] = 0.f; }

    // ================= pass 1: row max & sum =================
    for (int kt = 0; kt < 32; ++kt) {
#pragma unroll
        for (int i = 0; i < 2; ++i) {
            const int r = i * 32 + (t >> 3), c = (t & 7) * 8;
            *(bf16x8*)&Ks[r][c] = *(const bf16x8*)(Kp + (size_t)(kt * 64 + r) * kD + c);
        }
        __syncthreads();

        f32x4 s[2][4];
#pragma unroll
        for (int mf = 0; mf < 2; ++mf)
#pragma unroll
            for (int n = 0; n < 4; ++n) s[mf][n] = (f32x4){0.f, 0.f, 0.f, 0.f};
#pragma unroll
        for (int kq = 0; kq < 2; ++kq)
#pragma unroll
            for (int n = 0; n < 4; ++n) {
                const bf16x8 kb = *(const bf16x8*)&Ks[n * 16 + l16][kq * 32 + lhi * 8];
                s[0][n] = __builtin_amdgcn_mfma_f32_16x16x32_bf16(q[0][kq], kb, s[0][n], 0, 0, 0);
                s[1][n] = __builtin_amdgcn_mfma_f32_16x16x32_bf16(q[1][kq], kb, s[1][n], 0, 0, 0);
            }

#pragma unroll
        for (int mf = 0; mf < 2; ++mf)
#pragma unroll
            for (int j = 0; j < 4; ++j) {
                float mx = fmaxf(fmaxf(s[mf][0][j], s[mf][1][j]), fmaxf(s[mf][2][j], s[mf][3][j]));
#pragma unroll
                for (int off = 1; off < 16; off <<= 1) mx = fmaxf(mx, __shfl_xor(mx, off));
                const float mnew = fmaxf(mrow[mf][j], mx);
                float sum = __expf(s[mf][0][j] - mnew) + __expf(s[mf][1][j] - mnew)
                          + __expf(s[mf][2][j] - mnew) + __expf(s[mf][3][j] - mnew);
#pragma unroll
                for (int off = 1; off < 16; off <<= 1) sum += __shfl_xor(sum, off);
                lrow[mf][j] = lrow[mf][j] * __expf(mrow[mf][j] - mnew) + sum;
                mrow[mf][j] = mnew;
            }
        __syncthreads();
    }

    float invl[2][4];
#pragma unroll
    for (int mf = 0; mf < 2; ++mf)
#pragma unroll
        for (int j = 0; j < 4; ++j) invl[mf][j] = 1.0f / lrow[mf][j];

    // ================= pass 2: recompute S, write attn, O += P*V =========
    f32x4 o[2][4];
#pragma unroll
    for (int mf = 0; mf < 2; ++mf)
#pragma unroll
        for (int n = 0; n < 4; ++n) o[mf][n] = (f32x4){0.f, 0.f, 0.f, 0.f};

    for (int kt = 0; kt < 32; ++kt) {
#pragma unroll
        for (int i = 0; i < 2; ++i) {
            const int r = i * 32 + (t >> 3), c = (t & 7) * 8;
            *(bf16x8*)&Ks[r][c] = *(const bf16x8*)(Kp + (size_t)(kt * 64 + r) * kD + c);
            *(bf16x8*)&Vs[r][c] = *(const bf16x8*)(Vp + (size_t)r * kS + kt * 64 + c);
        }
        __syncthreads();

        f32x4 s[2][4];
#pragma unroll
        for (int mf = 0; mf < 2; ++mf)
#pragma unroll
            for (int n = 0; n < 4; ++n) s[mf][n] = (f32x4){0.f, 0.f, 0.f, 0.f};
#pragma unroll
        for (int kq = 0; kq < 2; ++kq)
#pragma unroll
            for (int n = 0; n < 4; ++n) {
                const bf16x8 kb = *(const bf16x8*)&Ks[n * 16 + l16][kq * 32 + lhi * 8];
                s[0][n] = __builtin_amdgcn_mfma_f32_16x16x32_bf16(q[0][kq], kb, s[0][n], 0, 0, 0);
                s[1][n] = __builtin_amdgcn_mfma_f32_16x16x32_bf16(q[1][kq], kb, s[1][n], 0, 0, 0);
            }

        // P = exp(s - m) / l; write attn f32 + Ps bf16
#pragma unroll
        for (int mf = 0; mf < 2; ++mf)
#pragma unroll
            for (int j = 0; j < 4; ++j) {
                const int qrow_l = w * 32 + mf * 16 + lhi * 4 + j;
                float* arow = Ap + (size_t)(qt * 128 + qrow_l) * kS + kt * 64;
#pragma unroll
                for (int n = 0; n < 4; ++n) {
                    const float p = __expf(s[mf][n][j] - mrow[mf][j]) * invl[mf][j];
                    arow[n * 16 + l16] = p;
                    Ps[qrow_l][n * 16 + l16] = f2bf(p);
                }
            }
        __syncthreads();   // Ps visible (cross-lane) before PV reads

#pragma unroll
        for (int ks = 0; ks < 2; ++ks) {
            bf16x8 pa[2];
#pragma unroll
            for (int mf = 0; mf < 2; ++mf)
                pa[mf] = *(const bf16x8*)&Ps[w * 32 + mf * 16 + l16][ks * 32 + lhi * 8];
#pragma unroll
            for (int n = 0; n < 4; ++n) {
                const bf16x8 vb = *(const bf16x8*)&Vs[n * 16 + l16][ks * 32 + lhi * 8];
                o[0][n] = __builtin_amdgcn_mfma_f32_16x16x32_bf16(pa[0], vb, o[0][n], 0, 0, 0);
                o[1][n] = __builtin_amdgcn_mfma_f32_16x16x32_bf16(pa[1], vb, o[1][n], 0, 0, 0);
            }
        }
        __syncthreads();   // all reads of Ks/Vs/Ps done before next stage
    }

    // ---- ctx write: [B,S,H*DV] bf16 ----
#pragma unroll
    for (int mf = 0; mf < 2; ++mf)
#pragma unroll
        for (int n = 0; n < 4; ++n)
#pragma unroll
            for (int j = 0; j < 4; ++j) {
                const int qg = qt * 128 + w * 32 + mf * 16 + lhi * 4 + j;
                const int dv = n * 16 + l16;
                ctx[((size_t)b * kS + qg) * kD + h * kDV + dv] = f2bf(o[mf][n][j]);
            }
}

// ---------------------------------------------------------------------------
extern "C" void kernel_launch(void* const* d_in, const int* in_sizes, int n_in,
                              void* d_out, int out_size, void* d_ws, size_t ws_size,
                              hipStream_t stream) {
    (void)in_sizes; (void)n_in; (void)out_size; (void)ws_size;

    const float* x      = (const float*)d_in[0];
    const float* w_qs   = (const float*)d_in[1];
    const float* w_ks   = (const float*)d_in[2];
    const float* w_vs   = (const float*)d_in[3];
    const float* fc_w   = (const float*)d_in[4];
    const float* fc_b   = (const float*)d_in[5];
    const float* ln1_g  = (const float*)d_in[6];
    const float* ln1_b  = (const float*)d_in[7];
    const float* ffn_w1 = (const float*)d_in[8];
    const float* ffn_b1 = (const float*)d_in[9];
    const float* ffn_w2 = (const float*)d_in[10];
    const float* ffn_b2 = (const float*)d_in[11];
    const float* ln2_g  = (const float*)d_in[12];
    const float* ln2_b  = (const float*)d_in[13];

    float* out_enc  = (float*)d_out;                   // [B,S,D] f32
    float* out_attn = out_enc + (size_t)kM * kD;       // [B,H,S,S] f32

    // Workspace (128 MB, same layout as round 2)
    unsigned short* xb   = (unsigned short*)d_ws;      // x bf16        8MB
    unsigned short* qinb = xb   + (size_t)4194304;     // LN1(x)
    unsigned short* Qb   = qinb + (size_t)4194304;     // Q
    unsigned short* Kb   = Qb   + (size_t)4194304;     // K
    unsigned short* Vt   = Kb   + (size_t)4194304;     // V^T
    unsigned short* ctxb = Vt   + (size_t)4194304;     // ctx
    unsigned short* hb   = ctxb + (size_t)4194304;     // LN2(attn_out)
    unsigned short* gb   = hb   + (size_t)4194304;     // gelu out 32MB
    unsigned short* wqsb = gb   + (size_t)16777216;    // weights bf16
    unsigned short* wksb = wqsb + (size_t)1048576;
    unsigned short* wvsb = wksb + (size_t)1048576;
    unsigned short* fcwb = wvsb + (size_t)1048576;
    unsigned short* w1b  = fcwb + (size_t)1048576;
    unsigned short* w2b  = w1b  + (size_t)4194304;
    float* attn_out      = (float*)(w2b + (size_t)4194304);  // f32 16MB

    const dim3 blk(256);

    // ---- converts ----
    cvt_bf16_kernel<<<2048, blk, 0, stream>>>(x, xb, kM * kD / 4);
    cvt_bf16_kernel<<<512, blk, 0, stream>>>(w_qs, wqsb, kD * kD / 4);
    cvt_bf16_kernel<<<512, blk, 0, stream>>>(w_ks, wksb, kD * kD / 4);
    cvt_bf16_kernel<<<512, blk, 0, stream>>>(w_vs, wvsb, kD * kD / 4);
    cvt_bf16_kernel<<<512, blk, 0, stream>>>(fc_w, fcwb, kD * kD / 4);
    cvt_bf16_kernel<<<2048, blk, 0, stream>>>(ffn_w1, w1b, kDFF * kD / 4);
    cvt_bf16_kernel<<<2048, blk, 0, stream>>>(ffn_w2, w2b, kDFF * kD / 4);

    // ---- LN1 ----
    ln_bf16_kernel<<<kM, blk, 0, stream>>>(x, ln1_g, ln1_b, qinb);

    // ---- Q/K/V projections (NT, bf16 out; V transposed) ----
    gemm_mfma<true, false, false, false, false><<<dim3(8, 32), blk, 0, stream>>>(
        qinb, kD, wqsb, kD, Qb, kD, nullptr, nullptr, 0, kD);
    gemm_mfma<true, false, false, false, false><<<dim3(8, 32), blk, 0, stream>>>(
        xb, kD, wksb, kD, Kb, kD, nullptr, nullptr, 0, kD);
    gemm_mfma<true, true, false, false, false><<<dim3(8, 32), blk, 0, stream>>>(
        xb, kD, wvsb, kD, Vt, 0, nullptr, nullptr, 0, kD);

    // ---- fused scores+softmax+PV: writes out_attn (f32) and ctxb (bf16) ----
    fused_attn<<<dim3(16, 32), blk, 0, stream>>>(Qb, Kb, Vt, out_attn, ctxb);

    // ---- attn_out = ctx @ fc_w^T + fc_b + x (f32) ----
    gemm_mfma<false, false, true, true, false><<<dim3(8, 32), blk, 0, stream>>>(
        ctxb, kD, fcwb, kD, attn_out, kD, fc_b, x, kD, kD);

    // ---- LN2 ----
    ln_bf16_kernel<<<kM, blk, 0, stream>>>(attn_out, ln2_g, ln2_b, hb);

    // ---- g = gelu(h @ ffn_w1^T + b1) -> bf16 ----
    gemm_mfma<true, false, true, false, true><<<dim3(32, 32), blk, 0, stream>>>(
        hb, kD, w1b, kD, gb, kDFF, ffn_b1, nullptr, 0, kD);

    // ---- enc_out = g @ ffn_w2^T + b2 + attn_out (f32) ----
    gemm_mfma<false, false, true, true, false><<<dim3(8, 32), blk, 0, stream>>>(
        gb, kDFF, w2b, kDFF, out_enc, kD, ffn_b2, attn_out, kD, kDFF);
}

// Round 5
// 551.786 us; speedup vs baseline: 3.8553x; 1.2039x over previous
//
#include <hip/hip_runtime.h>
#include <hip/hip_bf16.h>
#include <math.h>

typedef __attribute__((ext_vector_type(8))) short bf16x8;   // 8 bf16 in 4 VGPRs
typedef __attribute__((ext_vector_type(4))) float f32x4;
typedef __attribute__((ext_vector_type(4))) unsigned short u16x4;

namespace {
constexpr int kB = 2, kS = 2048, kD = 1024, kH = 16, kDK = 64, kDV = 64, kDFF = 4096;
constexpr float kEps = 1e-6f;
constexpr int kM = kB * kS;  // 4096
}

__device__ inline unsigned short f2bf(float f) {
    unsigned int u = __builtin_bit_cast(unsigned int, f);
    u += 0x7fffu + ((u >> 16) & 1u);   // round-nearest-even
    return (unsigned short)(u >> 16);
}
__device__ inline float bf2f(unsigned short u) {
    unsigned int x = ((unsigned int)u) << 16;
    return __builtin_bit_cast(float, x);
}

__device__ inline void gload_lds16(const void* g, void* l) {
    __builtin_amdgcn_global_load_lds(
        (const __attribute__((address_space(1))) unsigned int*)g,
        (__attribute__((address_space(3))) unsigned int*)l, 16, 0, 0);
}

// ---------------------------------------------------------------------------
// f32 -> bf16 convert (weights)
// ---------------------------------------------------------------------------
__global__ __launch_bounds__(256) void cvt_bf16_kernel(
    const float* __restrict__ in, unsigned short* __restrict__ out, int n4)
{
    int i = blockIdx.x * 256 + threadIdx.x;
    const int stride = gridDim.x * 256;
    for (; i < n4; i += stride) {
        const float4 v = ((const float4*)in)[i];
        u16x4 o;
        o.x = f2bf(v.x); o.y = f2bf(v.y); o.z = f2bf(v.z); o.w = f2bf(v.w);
        ((u16x4*)out)[i] = o;
    }
}

// ---------------------------------------------------------------------------
// LayerNorm, optionally also emitting the raw input as bf16 (saves a pass).
// One block per row, 256 threads, D=1024.
// ---------------------------------------------------------------------------
template<bool DUAL>
__global__ __launch_bounds__(256) void ln_bf16_kernel(
    const float* __restrict__ x, const float* __restrict__ g,
    const float* __restrict__ b, unsigned short* __restrict__ out,
    unsigned short* __restrict__ out_raw)
{
    const size_t row = blockIdx.x;
    const float4 v = ((const float4*)(x + row * kD))[threadIdx.x];
    if (DUAL) {
        u16x4 r;
        r.x = f2bf(v.x); r.y = f2bf(v.y); r.z = f2bf(v.z); r.w = f2bf(v.w);
        ((u16x4*)(out_raw + row * kD))[threadIdx.x] = r;
    }
    float s = v.x + v.y + v.z + v.w;
    float q = v.x * v.x + v.y * v.y + v.z * v.z + v.w * v.w;
#pragma unroll
    for (int off = 32; off > 0; off >>= 1) {
        s += __shfl_down(s, off);
        q += __shfl_down(q, off);
    }
    __shared__ float rs[4], rq[4];
    const int wid = threadIdx.x >> 6, lane = threadIdx.x & 63;
    if (lane == 0) { rs[wid] = s; rq[wid] = q; }
    __syncthreads();
    const float ts = rs[0] + rs[1] + rs[2] + rs[3];
    const float tq = rq[0] + rq[1] + rq[2] + rq[3];
    const float mean = ts * (1.0f / kD);
    const float var  = tq * (1.0f / kD) - mean * mean;
    const float rstd = rsqrtf(var + kEps);
    const float4 gg = ((const float4*)g)[threadIdx.x];
    const float4 bb = ((const float4*)b)[threadIdx.x];
    u16x4 o;
    o.x = f2bf((v.x - mean) * rstd * gg.x + bb.x);
    o.y = f2bf((v.y - mean) * rstd * gg.y + bb.y);
    o.z = f2bf((v.z - mean) * rstd * gg.z + bb.z);
    o.w = f2bf((v.w - mean) * rstd * gg.w + bb.w);
    ((u16x4*)(out + row * kD))[threadIdx.x] = o;
}

// ---------------------------------------------------------------------------
// Fused Q/K/V projection: one launch over N=3072 (Q|K|V). 128x128 tiles,
// m97 structure. Per-block A/B/output select (tiles never straddle the
// 1024-col boundaries). V is written transposed to Vt [B][H*DV][S].
// Grid (24, 32) = 768 blocks = 3/CU.
// ---------------------------------------------------------------------------
__global__ __launch_bounds__(256) void qkv_gemm(
    const unsigned short* __restrict__ qinb,  // LN1(x) bf16 [4096,1024]
    const unsigned short* __restrict__ xb,    // x bf16      [4096,1024]
    const unsigned short* __restrict__ wq,    // [1024,1024] bf16
    const unsigned short* __restrict__ wk,
    const unsigned short* __restrict__ wv,
    unsigned short* __restrict__ Qb,          // [4096,1024]
    unsigned short* __restrict__ Kb,          // [4096,1024]
    unsigned short* __restrict__ Vt)          // [B,1024,2048]
{
    __shared__ __align__(16) unsigned short As[128 * 32];
    __shared__ __align__(16) unsigned short Bs[128 * 32];

    const int m0  = blockIdx.y * 128;
    const int n0g = blockIdx.x * 128;
    const int which = n0g >> 10;          // 0=Q, 1=K, 2=V
    const int n0  = n0g & 1023;
    const unsigned short* A = (which == 0) ? qinb : xb;
    const unsigned short* B = (which == 0) ? wq : (which == 1 ? wk : wv);

    const int t = threadIdx.x;
    const int w = t >> 6, lane = t & 63;
    const int wm = (w >> 1) * 64;
    const int wn = (w & 1) * 64;

    f32x4 acc[4][4];
#pragma unroll
    for (int m = 0; m < 4; ++m)
#pragma unroll
        for (int n = 0; n < 4; ++n) acc[m][n] = (f32x4){0.f, 0.f, 0.f, 0.f};

    for (int k0 = 0; k0 < kD; k0 += 32) {
#pragma unroll
        for (int i = 0; i < 2; ++i) {
            const int r = i * 64 + (t >> 2);
            gload_lds16(A + (size_t)(m0 + r) * kD + k0 + (t & 3) * 8,
                        As + r * 32 + (t & 3) * 8);
            gload_lds16(B + (size_t)(n0 + r) * kD + k0 + (t & 3) * 8,
                        Bs + r * 32 + (t & 3) * 8);
        }
        __syncthreads();

        bf16x8 a[4], bb[4];
#pragma unroll
        for (int m = 0; m < 4; ++m)
            a[m] = *(const bf16x8*)(As + (wm + m * 16 + (lane & 15)) * 32 + (lane >> 4) * 8);
#pragma unroll
        for (int n = 0; n < 4; ++n)
            bb[n] = *(const bf16x8*)(Bs + (wn + n * 16 + (lane & 15)) * 32 + (lane >> 4) * 8);
#pragma unroll
        for (int m = 0; m < 4; ++m)
#pragma unroll
            for (int n = 0; n < 4; ++n)
                acc[m][n] = __builtin_amdgcn_mfma_f32_16x16x32_bf16(a[m], bb[n], acc[m][n], 0, 0, 0);
        __syncthreads();
    }

    const int col = lane & 15, rb = (lane >> 4) * 4;
#pragma unroll
    for (int m = 0; m < 4; ++m)
#pragma unroll
        for (int n = 0; n < 4; ++n)
#pragma unroll
            for (int j = 0; j < 4; ++j) {
                const int gm  = m0 + wm + m * 16 + rb + j;
                const int gnl = n0 + wn + n * 16 + col;
                const unsigned short bv = f2bf(acc[m][n][j]);
                if (which == 0)
                    Qb[(size_t)gm * kD + gnl] = bv;
                else if (which == 1)
                    Kb[(size_t)gm * kD + gnl] = bv;
                else
                    Vt[((size_t)(gm >> 11) * kD + gnl) * kS + (gm & 2047)] = bv;
            }
}

// ---------------------------------------------------------------------------
// bf16 MFMA GEMM (m97 structure): C[M,N] = A[M,K] @ B[N,K]^T (NT).
// 128 x BN tile, BK=32, 4 waves (2x2), 16x16x32 MFMA, global_load_lds(16B).
// ---------------------------------------------------------------------------
template<int BN, bool OUTB, bool BIAS, bool RES, bool GELU>
__global__ __launch_bounds__(256) void gemm_mfma(
    const unsigned short* __restrict__ A, int lda,
    const unsigned short* __restrict__ B, int ldb,
    void* __restrict__ Cbase, int ldc,
    const float* __restrict__ bias,
    const float* __restrict__ resbase, int ldres,
    int K)
{
    __shared__ __align__(16) unsigned short As[128 * 32];
    __shared__ __align__(16) unsigned short Bs[BN * 32];

    float* Cf = (float*)Cbase;
    unsigned short* Cu = (unsigned short*)Cbase;

    const int m0 = blockIdx.y * 128;
    const int n0 = blockIdx.x * BN;
    const int t = threadIdx.x;
    const int w = t >> 6, lane = t & 63;
    const int wm = (w >> 1) * 64;
    const int wn = (w & 1) * (BN / 2);
    constexpr int AN = (BN / 2) / 16;     // 4 for BN=128, 2 for BN=64

    f32x4 acc[4][AN];
#pragma unroll
    for (int m = 0; m < 4; ++m)
#pragma unroll
        for (int n = 0; n < AN; ++n) acc[m][n] = (f32x4){0.f, 0.f, 0.f, 0.f};

    for (int k0 = 0; k0 < K; k0 += 32) {
#pragma unroll
        for (int i = 0; i < 2; ++i) {
            const int r = i * 64 + (t >> 2);
            gload_lds16(A + (size_t)(m0 + r) * lda + k0 + (t & 3) * 8,
                        As + r * 32 + (t & 3) * 8);
        }
#pragma unroll
        for (int i = 0; i < BN / 64; ++i) {
            const int r = i * 64 + (t >> 2);
            gload_lds16(B + (size_t)(n0 + r) * ldb + k0 + (t & 3) * 8,
                        Bs + r * 32 + (t & 3) * 8);
        }
        __syncthreads();

        bf16x8 a[4], bb[AN];
#pragma unroll
        for (int m = 0; m < 4; ++m)
            a[m] = *(const bf16x8*)(As + (wm + m * 16 + (lane & 15)) * 32 + (lane >> 4) * 8);
#pragma unroll
        for (int n = 0; n < AN; ++n)
            bb[n] = *(const bf16x8*)(Bs + (wn + n * 16 + (lane & 15)) * 32 + (lane >> 4) * 8);
#pragma unroll
        for (int m = 0; m < 4; ++m)
#pragma unroll
            for (int n = 0; n < AN; ++n)
                acc[m][n] = __builtin_amdgcn_mfma_f32_16x16x32_bf16(a[m], bb[n], acc[m][n], 0, 0, 0);
        __syncthreads();
    }

    const int col = lane & 15, rb = (lane >> 4) * 4;
#pragma unroll
    for (int m = 0; m < 4; ++m)
#pragma unroll
        for (int n = 0; n < AN; ++n)
#pragma unroll
            for (int j = 0; j < 4; ++j) {
                const int gm = m0 + wm + m * 16 + rb + j;
                const int gn = n0 + wn + n * 16 + col;
                float v = acc[m][n][j];
                if (BIAS) v += bias[gn];
                if (GELU) v = 0.5f * v * (1.0f + erff(v * 0.7071067811865476f));
                if (RES)  v += resbase[(size_t)gm * ldres + gn];
                if (OUTB) Cu[(size_t)gm * ldc + gn] = f2bf(v);
                else      Cf[(size_t)gm * ldc + gn] = v;
            }
}

// ---------------------------------------------------------------------------
// Fused attention: per block = one (b,h) x one 128-row Q tile.
// Two passes over 32 K/V tiles of 64 keys. 4 waves x 32 q-rows each.
// Pass 2 stages P in LDS (bf16), then writes attn as 128B-contiguous
// nontemporal f32x4 streams and feeds PV MFMA from the same LDS tile.
// ---------------------------------------------------------------------------
__global__ __launch_bounds__(256) void fused_attn(
    const unsigned short* __restrict__ Qb,   // [B,S,H*DK] bf16
    const unsigned short* __restrict__ Kb,   // [B,S,H*DK] bf16
    const unsigned short* __restrict__ Vt,   // [B,H*DV,S] bf16
    float* __restrict__ attn,                // [B,H,S,S] f32
    unsigned short* __restrict__ ctx)        // [B,S,H*DV] bf16
{
    __shared__ __align__(16) unsigned short Ks[64][72];
    __shared__ __align__(16) unsigned short Vs[64][72];
    __shared__ __align__(16) unsigned short Ps[128][72];

    const int z = blockIdx.y, b = z >> 4, h = z & 15;
    const int qt = blockIdx.x;
    const int t = threadIdx.x, w = t >> 6, lane = t & 63;
    const int l16 = lane & 15, lhi = lane >> 4;

    const unsigned short* Qp = Qb + (size_t)b * kS * kD + (size_t)h * kDK;
    const unsigned short* Kp = Kb + (size_t)b * kS * kD + (size_t)h * kDK;
    const unsigned short* Vp = Vt + (size_t)(b * kD + h * kDV) * kS;
    float* Ap = attn + (size_t)z * kS * kS;

    // ---- Q fragments in registers, pre-scaled by 1/8 (exact in bf16) ----
    bf16x8 q[2][2];
    const int qrow0 = qt * 128 + w * 32;
#pragma unroll
    for (int mf = 0; mf < 2; ++mf)
#pragma unroll
        for (int kq = 0; kq < 2; ++kq) {
            bf16x8 v = *(const bf16x8*)(Qp + (size_t)(qrow0 + mf * 16 + l16) * kD + kq * 32 + lhi * 8);
#pragma unroll
            for (int e = 0; e < 8; ++e)
                v[e] = (short)f2bf(bf2f((unsigned short)v[e]) * 0.125f);
            q[mf][kq] = v;
        }

    float mrow[2][4], lrow[2][4];
#pragma unroll
    for (int mf = 0; mf < 2; ++mf)
#pragma unroll
        for (int j = 0; j < 4; ++j) { mrow[mf][j] = -1e30f; lrow[mf][j] = 0.f; }

    // ================= pass 1: row max & sum =================
    for (int kt = 0; kt < 32; ++kt) {
#pragma unroll
        for (int i = 0; i < 2; ++i) {
            const int r = i * 32 + (t >> 3), c = (t & 7) * 8;
            *(bf16x8*)&Ks[r][c] = *(const bf16x8*)(Kp + (size_t)(kt * 64 + r) * kD + c);
        }
        __syncthreads();

        f32x4 s[2][4];
#pragma unroll
        for (int mf = 0; mf < 2; ++mf)
#pragma unroll
            for (int n = 0; n < 4; ++n) s[mf][n] = (f32x4){0.f, 0.f, 0.f, 0.f};
#pragma unroll
        for (int kq = 0; kq < 2; ++kq)
#pragma unroll
            for (int n = 0; n < 4; ++n) {
                const bf16x8 kb = *(const bf16x8*)&Ks[n * 16 + l16][kq * 32 + lhi * 8];
                s[0][n] = __builtin_amdgcn_mfma_f32_16x16x32_bf16(q[0][kq], kb, s[0][n], 0, 0, 0);
                s[1][n] = __builtin_amdgcn_mfma_f32_16x16x32_bf16(q[1][kq], kb, s[1][n], 0, 0, 0);
            }

#pragma unroll
        for (int mf = 0; mf < 2; ++mf)
#pragma unroll
            for (int j = 0; j < 4; ++j) {
                float mx = fmaxf(fmaxf(s[mf][0][j], s[mf][1][j]), fmaxf(s[mf][2][j], s[mf][3][j]));
#pragma unroll
                for (int off = 1; off < 16; off <<= 1) mx = fmaxf(mx, __shfl_xor(mx, off));
                const float mnew = fmaxf(mrow[mf][j], mx);
                float sum = __expf(s[mf][0][j] - mnew) + __expf(s[mf][1][j] - mnew)
                          + __expf(s[mf][2][j] - mnew) + __expf(s[mf][3][j] - mnew);
#pragma unroll
                for (int off = 1; off < 16; off <<= 1) sum += __shfl_xor(sum, off);
                lrow[mf][j] = lrow[mf][j] * __expf(mrow[mf][j] - mnew) + sum;
                mrow[mf][j] = mnew;
            }
        __syncthreads();
    }

    float invl[2][4];
#pragma unroll
    for (int mf = 0; mf < 2; ++mf)
#pragma unroll
        for (int j = 0; j < 4; ++j) invl[mf][j] = 1.0f / lrow[mf][j];

    // ================= pass 2: recompute S, write attn, O += P*V =========
    f32x4 o[2][4];
#pragma unroll
    for (int mf = 0; mf < 2; ++mf)
#pragma unroll
        for (int n = 0; n < 4; ++n) o[mf][n] = (f32x4){0.f, 0.f, 0.f, 0.f};

    for (int kt = 0; kt < 32; ++kt) {
#pragma unroll
        for (int i = 0; i < 2; ++i) {
            const int r = i * 32 + (t >> 3), c = (t & 7) * 8;
            *(bf16x8*)&Ks[r][c] = *(const bf16x8*)(Kp + (size_t)(kt * 64 + r) * kD + c);
            *(bf16x8*)&Vs[r][c] = *(const bf16x8*)(Vp + (size_t)r * kS + kt * 64 + c);
        }
        __syncthreads();

        f32x4 s[2][4];
#pragma unroll
        for (int mf = 0; mf < 2; ++mf)
#pragma unroll
            for (int n = 0; n < 4; ++n) s[mf][n] = (f32x4){0.f, 0.f, 0.f, 0.f};
#pragma unroll
        for (int kq = 0; kq < 2; ++kq)
#pragma unroll
            for (int n = 0; n < 4; ++n) {
                const bf16x8 kb = *(const bf16x8*)&Ks[n * 16 + l16][kq * 32 + lhi * 8];
                s[0][n] = __builtin_amdgcn_mfma_f32_16x16x32_bf16(q[0][kq], kb, s[0][n], 0, 0, 0);
                s[1][n] = __builtin_amdgcn_mfma_f32_16x16x32_bf16(q[1][kq], kb, s[1][n], 0, 0, 0);
            }

        // P = exp(s - m) / l -> Ps (bf16)
#pragma unroll
        for (int mf = 0; mf < 2; ++mf)
#pragma unroll
            for (int j = 0; j < 4; ++j) {
                const int qrow_l = w * 32 + mf * 16 + lhi * 4 + j;
#pragma unroll
                for (int n = 0; n < 4; ++n) {
                    const float p = __expf(s[mf][n][j] - mrow[mf][j]) * invl[mf][j];
                    Ps[qrow_l][n * 16 + l16] = f2bf(p);
                }
            }
        __syncthreads();   // Ps visible before PV reads + attn writeback

        // attn writeback: contiguous 128B-per-8-lane nontemporal f32x4 streams
#pragma unroll
        for (int rg = 0; rg < 4; ++rg) {
            const int row = rg * 32 + (t >> 3);
            const int cb  = (t & 7) * 8;
            const bf16x8 pv = *(const bf16x8*)&Ps[row][cb];
            f32x4 f0, f1;
            f0.x = bf2f((unsigned short)pv[0]); f0.y = bf2f((unsigned short)pv[1]);
            f0.z = bf2f((unsigned short)pv[2]); f0.w = bf2f((unsigned short)pv[3]);
            f1.x = bf2f((unsigned short)pv[4]); f1.y = bf2f((unsigned short)pv[5]);
            f1.z = bf2f((unsigned short)pv[6]); f1.w = bf2f((unsigned short)pv[7]);
            float* dst = Ap + (size_t)(qt * 128 + row) * kS + kt * 64 + cb;
            __builtin_nontemporal_store(f0, (f32x4*)dst);
            __builtin_nontemporal_store(f1, (f32x4*)(dst + 4));
        }

#pragma unroll
        for (int ks = 0; ks < 2; ++ks) {
            bf16x8 pa[2];
#pragma unroll
            for (int mf = 0; mf < 2; ++mf)
                pa[mf] = *(const bf16x8*)&Ps[w * 32 + mf * 16 + l16][ks * 32 + lhi * 8];
#pragma unroll
            for (int n = 0; n < 4; ++n) {
                const bf16x8 vb = *(const bf16x8*)&Vs[n * 16 + l16][ks * 32 + lhi * 8];
                o[0][n] = __builtin_amdgcn_mfma_f32_16x16x32_bf16(pa[0], vb, o[0][n], 0, 0, 0);
                o[1][n] = __builtin_amdgcn_mfma_f32_16x16x32_bf16(pa[1], vb, o[1][n], 0, 0, 0);
            }
        }
        __syncthreads();   // all reads of Ks/Vs/Ps done before next stage
    }

    // ---- ctx write: [B,S,H*DV] bf16 ----
#pragma unroll
    for (int mf = 0; mf < 2; ++mf)
#pragma unroll
        for (int n = 0; n < 4; ++n)
#pragma unroll
            for (int j = 0; j < 4; ++j) {
                const int qg = qt * 128 + w * 32 + mf * 16 + lhi * 4 + j;
                const int dv = n * 16 + l16;
                ctx[((size_t)b * kS + qg) * kD + h * kDV + dv] = f2bf(o[mf][n][j]);
            }
}

// ---------------------------------------------------------------------------
extern "C" void kernel_launch(void* const* d_in, const int* in_sizes, int n_in,
                              void* d_out, int out_size, void* d_ws, size_t ws_size,
                              hipStream_t stream) {
    (void)in_sizes; (void)n_in; (void)out_size; (void)ws_size;

    const float* x      = (const float*)d_in[0];
    const float* w_qs   = (const float*)d_in[1];
    const float* w_ks   = (const float*)d_in[2];
    const float* w_vs   = (const float*)d_in[3];
    const float* fc_w   = (const float*)d_in[4];
    const float* fc_b   = (const float*)d_in[5];
    const float* ln1_g  = (const float*)d_in[6];
    const float* ln1_b  = (const float*)d_in[7];
    const float* ffn_w1 = (const float*)d_in[8];
    const float* ffn_b1 = (const float*)d_in[9];
    const float* ffn_w2 = (const float*)d_in[10];
    const float* ffn_b2 = (const float*)d_in[11];
    const float* ln2_g  = (const float*)d_in[12];
    const float* ln2_b  = (const float*)d_in[13];

    float* out_enc  = (float*)d_out;                   // [B,S,D] f32
    float* out_attn = out_enc + (size_t)kM * kD;       // [B,H,S,S] f32

    // Workspace (128 MB)
    unsigned short* xb   = (unsigned short*)d_ws;      // x bf16
    unsigned short* qinb = xb   + (size_t)4194304;     // LN1(x)
    unsigned short* Qb   = qinb + (size_t)4194304;     // Q
    unsigned short* Kb   = Qb   + (size_t)4194304;     // K
    unsigned short* Vt   = Kb   + (size_t)4194304;     // V^T
    unsigned short* ctxb = Vt   + (size_t)4194304;     // ctx
    unsigned short* hb   = ctxb + (size_t)4194304;     // LN2(attn_out)
    unsigned short* gb   = hb   + (size_t)4194304;     // gelu out
    unsigned short* wqsb = gb   + (size_t)16777216;    // weights bf16
    unsigned short* wksb = wqsb + (size_t)1048576;
    unsigned short* wvsb = wksb + (size_t)1048576;
    unsigned short* fcwb = wvsb + (size_t)1048576;
    unsigned short* w1b  = fcwb + (size_t)1048576;
    unsigned short* w2b  = w1b  + (size_t)4194304;
    float* attn_out      = (float*)(w2b + (size_t)4194304);  // f32 16MB

    const dim3 blk(256);

    // ---- weight converts ----
    cvt_bf16_kernel<<<512, blk, 0, stream>>>(w_qs, wqsb, kD * kD / 4);
    cvt_bf16_kernel<<<512, blk, 0, stream>>>(w_ks, wksb, kD * kD / 4);
    cvt_bf16_kernel<<<512, blk, 0, stream>>>(w_vs, wvsb, kD * kD / 4);
    cvt_bf16_kernel<<<512, blk, 0, stream>>>(fc_w, fcwb, kD * kD / 4);
    cvt_bf16_kernel<<<2048, blk, 0, stream>>>(ffn_w1, w1b, kDFF * kD / 4);
    cvt_bf16_kernel<<<2048, blk, 0, stream>>>(ffn_w2, w2b, kDFF * kD / 4);

    // ---- LN1 (also emits x as bf16) ----
    ln_bf16_kernel<true><<<kM, blk, 0, stream>>>(x, ln1_g, ln1_b, qinb, xb);

    // ---- fused Q/K/V projections ----
    qkv_gemm<<<dim3(24, 32), blk, 0, stream>>>(qinb, xb, wqsb, wksb, wvsb, Qb, Kb, Vt);

    // ---- fused scores+softmax+PV: writes out_attn (f32) and ctxb (bf16) ----
    fused_attn<<<dim3(16, 32), blk, 0, stream>>>(Qb, Kb, Vt, out_attn, ctxb);

    // ---- attn_out = ctx @ fc_w^T + fc_b + x (f32) ----
    gemm_mfma<64, false, true, true, false><<<dim3(16, 32), blk, 0, stream>>>(
        ctxb, kD, fcwb, kD, attn_out, kD, fc_b, x, kD, kD);

    // ---- LN2 ----
    ln_bf16_kernel<false><<<kM, blk, 0, stream>>>(attn_out, ln2_g, ln2_b, hb, nullptr);

    // ---- g = gelu(h @ ffn_w1^T + b1) -> bf16 ----
    gemm_mfma<128, true, true, false, true><<<dim3(32, 32), blk, 0, stream>>>(
        hb, kD, w1b, kD, gb, kDFF, ffn_b1, nullptr, 0, kD);

    // ---- enc_out = g @ ffn_w2^T + b2 + attn_out (f32) ----
    gemm_mfma<64, false, true, true, false><<<dim3(16, 32), blk, 0, stream>>>(
        gb, kDFF, w2b, kDFF, out_enc, kD, ffn_b2, attn_out, kD, kDFF);
}